// Round 13
// baseline (285.050 us; speedup 1.0000x reference)
//
#include <hip/hip_runtime.h>
#include <hip/hip_bf16.h>

#define BN 16384
#define NPTS 8192
#define KNN 16

typedef __attribute__((ext_vector_type(8))) short bf16x8;
typedef __attribute__((ext_vector_type(4))) float f32x4;
typedef __attribute__((ext_vector_type(4))) unsigned short u16x4;

static __device__ __forceinline__ unsigned short f2bf(float f) {
    union { float f; unsigned u; } v; v.f = f;
    unsigned r = v.u + 0x7fffu + ((v.u >> 16) & 1u);
    return (unsigned short)(r >> 16);
}

static __device__ __forceinline__ float rfl(float v) {
    return __int_as_float(__builtin_amdgcn_readfirstlane(__float_as_int(v)));
}

// ---------------- pack xyz -> float4(x,y,z,|x|^2) ----------------
__global__ __launch_bounds__(256) void pack_xyz(const float* __restrict__ xyz,
                                                float4* __restrict__ xyz4) {
    int i = blockIdx.x * 256 + threadIdx.x;
    if (i < BN) {
        float x = xyz[i * 3 + 0], y = xyz[i * 3 + 1], z = xyz[i * 3 + 2];
        xyz4[i] = make_float4(x, y, z, x * x + y * y + z * z);
    }
}

// ---------------- KNN: register-buffered survivor compaction ----------------
// d' = |c|^2 - 2 q.c (row-constant shift: selection invariant). Queries in
// SGPRs. Threshold = max over 16 disjoint 16-lane-group minima (count>=16
// guaranteed, E[survivors]~51/row, cap 256). Pass B: survivors buffered in 6
// static register slots per thread (E~1.6, no in-loop LDS atomic chain);
// exec-masked immediate-atomic fallback on slot overflow keeps exactness.
// Exact rank with index tie-break == stable top_k.
__global__ __launch_bounds__(256, 8) void knn_kernel(const float4* __restrict__ xyz4,
                                                     int* __restrict__ knn_idx) {
    __shared__ float wmaxs[4][8];
    __shared__ int   cnt[8];
    __shared__ float ckey[8 * 256];
    __shared__ int   cidx[8 * 256];
    int tid = threadIdx.x, lane = tid & 63, w = tid >> 6;
    int r0 = blockIdx.x * 8;
    int b = r0 >> 13;
    const float4* __restrict__ base = xyz4 + b * NPTS;

    float qx[8], qy[8], qz[8], minv[8];
#pragma unroll
    for (int rr = 0; rr < 8; rr++) {
        float4 q = xyz4[r0 + rr];
        qx[rr] = -2.f * q.x; qy[rr] = -2.f * q.y; qz[rr] = -2.f * q.z;
        minv[rr] = 3e38f;
    }
    if (tid < 8) cnt[tid] = 0;

    // ---- Pass A: per-(lane,row) min of d' ----
#pragma unroll 4
    for (int i = 0; i < 32; i++) {
        float4 c = base[tid + (i << 8)];
#pragma unroll
        for (int rr = 0; rr < 8; rr++) {
            float d = fmaf(qx[rr], c.x, fmaf(qy[rr], c.y, fmaf(qz[rr], c.z, c.w)));
            minv[rr] = fminf(minv[rr], d);
        }
    }

#pragma unroll
    for (int rr = 0; rr < 8; rr++) {
        float v = minv[rr];
        v = fminf(v, __shfl_xor(v, 1, 64));
        v = fminf(v, __shfl_xor(v, 2, 64));
        v = fminf(v, __shfl_xor(v, 4, 64));
        v = fminf(v, __shfl_xor(v, 8, 64));
        v = fmaxf(v, __shfl_xor(v, 16, 64));
        v = fmaxf(v, __shfl_xor(v, 32, 64));
        if (lane == 0) wmaxs[w][rr] = v;
    }
    __syncthreads();
    float T[8];
#pragma unroll
    for (int rr = 0; rr < 8; rr++)
        T[rr] = rfl(fmaxf(fmaxf(wmaxs[0][rr], wmaxs[1][rr]),
                          fmaxf(wmaxs[2][rr], wmaxs[3][rr])));

    // ---- Pass B: bit-identical recompute, register-slot compaction ----
    float sd0 = 0.f, sd1 = 0.f, sd2 = 0.f, sd3 = 0.f, sd4 = 0.f, sd5 = 0.f;
    int sm0 = 0, sm1 = 0, sm2 = 0, sm3 = 0, sm4 = 0, sm5 = 0;
    int myCnt = 0;
#pragma unroll 2
    for (int i = 0; i < 32; i++) {
        float4 c = base[tid + (i << 8)];
#pragma unroll
        for (int rr = 0; rr < 8; rr++) {
            float d = fmaf(qx[rr], c.x, fmaf(qy[rr], c.y, fmaf(qz[rr], c.z, c.w)));
            if (d <= T[rr]) {
                int meta = (rr << 13) | (tid + (i << 8));
                if (myCnt == 0)      { sd0 = d; sm0 = meta; }
                else if (myCnt == 1) { sd1 = d; sm1 = meta; }
                else if (myCnt == 2) { sd2 = d; sm2 = meta; }
                else if (myCnt == 3) { sd3 = d; sm3 = meta; }
                else if (myCnt == 4) { sd4 = d; sm4 = meta; }
                else if (myCnt == 5) { sd5 = d; sm5 = meta; }
                else {
                    // rare overflow: immediate atomic path (exactness preserved)
                    int p = atomicAdd(&cnt[rr], 1);
                    if (p < 256) { ckey[rr * 256 + p] = d; cidx[rr * 256 + p] = tid + (i << 8); }
                }
                myCnt++;
            }
        }
    }
    // ---- flush register slots (latency chains batched outside hot loop) ----
    {
        float fd[6] = {sd0, sd1, sd2, sd3, sd4, sd5};
        int   fm[6] = {sm0, sm1, sm2, sm3, sm4, sm5};
        int nflush = min(myCnt, 6);
#pragma unroll
        for (int j = 0; j < 6; j++) {
            if (j < nflush) {
                int rr = fm[j] >> 13;
                int idx = fm[j] & 8191;
                int p = atomicAdd(&cnt[rr], 1);
                if (p < 256) { ckey[rr * 256 + p] = fd[j]; cidx[rr * 256 + p] = idx; }
            }
        }
    }
    __syncthreads();

    // ---- exact rank among survivors; wave w handles rows w and w+4 ----
    for (int rr = w; rr < 8; rr += 4) {
        int cc = min(cnt[rr], 256);
        for (int s = lane; s < cc; s += 64) {
            float myk = ckey[rr * 256 + s]; int myi = cidx[rr * 256 + s];
            int rank = 0;
            for (int j2 = 0; j2 < cc; j2++) {
                float kj = ckey[rr * 256 + j2]; int ij = cidx[rr * 256 + j2];
                rank += (kj < myk || (kj == myk && ij < myi)) ? 1 : 0;
            }
            if (rank < 16) knn_idx[(r0 + rr) * 16 + rank] = myi;
        }
    }
}

// ---------------- Q/K/V projections via MFMA ----------------
__global__ __launch_bounds__(256) void qkv_mfma(const float* __restrict__ feats,
                                                const float* __restrict__ wq,
                                                const float* __restrict__ wk,
                                                const float* __restrict__ wv,
                                                float* __restrict__ Q,
                                                float* __restrict__ Kf,
                                                float* __restrict__ Vf) {
    __shared__ __align__(16) unsigned short sW[3][64 * 68];
    int tid = threadIdx.x;
    int w = tid >> 6, lane = tid & 63, quad = lane >> 4, col = lane & 15;

    for (int i = tid; i < 4096; i += 256) {
        int k = i >> 6, n = i & 63;
        sW[0][n * 68 + k] = f2bf(wq[i]);
        sW[1][n * 68 + k] = f2bf(wk[i]);
        sW[2][n * 68 + k] = f2bf(wv[i]);
    }
    __syncthreads();

    int row0 = blockIdx.x * 64 + w * 16;
    bf16x8 a0, a1;
    {
        const float* fp = feats + (row0 + col) * 64 + quad * 8;
        float4 x0 = *(const float4*)fp,        x1 = *(const float4*)(fp + 4);
        float4 x2 = *(const float4*)(fp + 32), x3 = *(const float4*)(fp + 36);
        a0[0] = (short)f2bf(x0.x); a0[1] = (short)f2bf(x0.y); a0[2] = (short)f2bf(x0.z); a0[3] = (short)f2bf(x0.w);
        a0[4] = (short)f2bf(x1.x); a0[5] = (short)f2bf(x1.y); a0[6] = (short)f2bf(x1.z); a0[7] = (short)f2bf(x1.w);
        a1[0] = (short)f2bf(x2.x); a1[1] = (short)f2bf(x2.y); a1[2] = (short)f2bf(x2.z); a1[3] = (short)f2bf(x2.w);
        a1[4] = (short)f2bf(x3.x); a1[5] = (short)f2bf(x3.y); a1[6] = (short)f2bf(x3.z); a1[7] = (short)f2bf(x3.w);
    }

    float* outs[3] = {Q, Kf, Vf};
#pragma unroll
    for (int mat = 0; mat < 3; mat++) {
        float* out = outs[mat];
#pragma unroll
        for (int nt = 0; nt < 4; nt++) {
            bf16x8 b0, b1;
            {
                const unsigned short* p0 = &sW[mat][(nt * 16 + col) * 68 + quad * 8];
                u16x4 l0 = *(const u16x4*)p0, h0 = *(const u16x4*)(p0 + 4);
                u16x4 l1 = *(const u16x4*)(p0 + 32), h1 = *(const u16x4*)(p0 + 36);
#pragma unroll
                for (int z = 0; z < 4; z++) { b0[z] = (short)l0[z]; b0[z+4] = (short)h0[z]; b1[z] = (short)l1[z]; b1[z+4] = (short)h1[z]; }
            }
            f32x4 acc = {0.f, 0.f, 0.f, 0.f};
            acc = __builtin_amdgcn_mfma_f32_16x16x32_bf16(a0, b0, acc, 0, 0, 0);
            acc = __builtin_amdgcn_mfma_f32_16x16x32_bf16(a1, b1, acc, 0, 0, 0);
#pragma unroll
            for (int r = 0; r < 4; r++)
                out[(row0 + quad * 4 + r) * 64 + nt * 16 + col] = acc[r];
        }
    }
}

// ---------------- fused attention + BN partial sums ----------------
__global__ __launch_bounds__(256, 2) void attn_mfma(
    const float4* __restrict__ xyz4, const int* __restrict__ knn_idx,
    const float* __restrict__ Q, const float* __restrict__ Kf, const float* __restrict__ Vf,
    const float* __restrict__ feats,
    const float* __restrict__ dw1, const float* __restrict__ db1,
    const float* __restrict__ dw2, const float* __restrict__ db2,
    const float* __restrict__ gw1, const float* __restrict__ gb1,
    const float* __restrict__ gw2,
    float* __restrict__ res, float* __restrict__ accum) {
    __shared__ __align__(16) unsigned short sWd2[64 * 68];
    __shared__ __align__(16) unsigned short sWg1[64 * 68];
    __shared__ __align__(16) unsigned short sWg2[64 * 68];
    __shared__ __align__(16) unsigned short sA[256 * 72];
    __shared__ int sidx[256];
    __shared__ float sdw1[256];

    int tid = threadIdx.x;
    int w = tid >> 6, lane = tid & 63, quad = lane >> 4, col = lane & 15;
    int r0 = blockIdx.x * 16;

    for (int i = tid; i < 4096; i += 256) {
        int e = i >> 6, c = i & 63;
        sWd2[c * 68 + e] = f2bf(dw2[i]);
        sWg1[c * 68 + e] = f2bf(gw1[i]);
        sWg2[c * 68 + e] = f2bf(gw2[i]);
    }
    if (tid < 192) sdw1[tid] = dw1[tid];
    else sdw1[tid] = db1[tid - 192];
    {
        int brow = r0 + (tid >> 4);
        int b = brow >> 13;
        sidx[tid] = b * NPTS + knn_idx[brow * 16 + (tid & 15)];
    }
    __syncthreads();

    {
        int m = tid;
        int brow = r0 + (m >> 4);
        float4 p = xyz4[brow];
        float4 nb = xyz4[sidx[m]];
        float rx = p.x - nb.x, ry = p.y - nb.y, rz = p.z - nb.z;
        for (int c0 = 0; c0 < 64; c0 += 8) {
            bf16x8 v;
#pragma unroll
            for (int cc = 0; cc < 8; cc++) {
                int c = c0 + cc;
                float h = sdw1[192 + c] + rx * sdw1[c] + ry * sdw1[64 + c] + rz * sdw1[128 + c];
                v[cc] = (short)f2bf(fmaxf(h, 0.f));
            }
            *(bf16x8*)&sA[m * 72 + c0] = v;
        }
    }

    int m0 = w * 64;
    bf16x8 af[4][2];

#pragma unroll
    for (int mt = 0; mt < 4; mt++)
#pragma unroll
        for (int k2 = 0; k2 < 2; k2++)
            af[mt][k2] = *(const bf16x8*)&sA[(m0 + mt * 16 + col) * 72 + quad * 8 + k2 * 32];

    f32x4 pos[4][4];
#pragma unroll
    for (int nt = 0; nt < 4; nt++) {
        float bias = db2[nt * 16 + col];
        bf16x8 b0, b1;
        {
            const unsigned short* p0 = &sWd2[(nt * 16 + col) * 68 + quad * 8];
            u16x4 l0 = *(const u16x4*)p0, h0 = *(const u16x4*)(p0 + 4);
            u16x4 l1 = *(const u16x4*)(p0 + 32), h1 = *(const u16x4*)(p0 + 36);
#pragma unroll
            for (int z = 0; z < 4; z++) { b0[z] = (short)l0[z]; b0[z+4] = (short)h0[z]; b1[z] = (short)l1[z]; b1[z+4] = (short)h1[z]; }
        }
#pragma unroll
        for (int mt = 0; mt < 4; mt++) {
            f32x4 acc = {bias, bias, bias, bias};
            acc = __builtin_amdgcn_mfma_f32_16x16x32_bf16(af[mt][0], b0, acc, 0, 0, 0);
            acc = __builtin_amdgcn_mfma_f32_16x16x32_bf16(af[mt][1], b1, acc, 0, 0, 0);
            pos[mt][nt] = acc;
        }
    }

#pragma unroll
    for (int mt = 0; mt < 4; mt++) {
        int row = r0 + w * 4 + mt;
        int gx[4];
#pragma unroll
        for (int r = 0; r < 4; r++) gx[r] = sidx[w * 64 + mt * 16 + quad * 4 + r];
#pragma unroll
        for (int nt = 0; nt < 4; nt++) {
            int c = nt * 16 + col;
            float qv = Q[row * 64 + c];
#pragma unroll
            for (int r = 0; r < 4; r++) {
                float tv = qv - Kf[gx[r] * 64 + c] + pos[mt][nt][r];
                sA[(m0 + mt * 16 + quad * 4 + r) * 72 + c] = f2bf(tv);
            }
        }
    }

#pragma unroll
    for (int mt = 0; mt < 4; mt++)
#pragma unroll
        for (int k2 = 0; k2 < 2; k2++)
            af[mt][k2] = *(const bf16x8*)&sA[(m0 + mt * 16 + col) * 72 + quad * 8 + k2 * 32];

    f32x4 cc4[4][4];
#pragma unroll
    for (int nt = 0; nt < 4; nt++) {
        float bias = gb1[nt * 16 + col];
        bf16x8 b0, b1;
        {
            const unsigned short* p0 = &sWg1[(nt * 16 + col) * 68 + quad * 8];
            u16x4 l0 = *(const u16x4*)p0, h0 = *(const u16x4*)(p0 + 4);
            u16x4 l1 = *(const u16x4*)(p0 + 32), h1 = *(const u16x4*)(p0 + 36);
#pragma unroll
            for (int z = 0; z < 4; z++) { b0[z] = (short)l0[z]; b0[z+4] = (short)h0[z]; b1[z] = (short)l1[z]; b1[z+4] = (short)h1[z]; }
        }
#pragma unroll
        for (int mt = 0; mt < 4; mt++) {
            f32x4 acc = {bias, bias, bias, bias};
            acc = __builtin_amdgcn_mfma_f32_16x16x32_bf16(af[mt][0], b0, acc, 0, 0, 0);
            acc = __builtin_amdgcn_mfma_f32_16x16x32_bf16(af[mt][1], b1, acc, 0, 0, 0);
            cc4[mt][nt] = acc;
        }
    }
#pragma unroll
    for (int mt = 0; mt < 4; mt++)
#pragma unroll
        for (int nt = 0; nt < 4; nt++)
#pragma unroll
            for (int r = 0; r < 4; r++)
                sA[(m0 + mt * 16 + quad * 4 + r) * 72 + nt * 16 + col] = f2bf(fmaxf(cc4[mt][nt][r], 0.f));

#pragma unroll
    for (int mt = 0; mt < 4; mt++)
#pragma unroll
        for (int k2 = 0; k2 < 2; k2++)
            af[mt][k2] = *(const bf16x8*)&sA[(m0 + mt * 16 + col) * 72 + quad * 8 + k2 * 32];

#pragma unroll
    for (int nt = 0; nt < 4; nt++) {
        bf16x8 b0, b1;
        {
            const unsigned short* p0 = &sWg2[(nt * 16 + col) * 68 + quad * 8];
            u16x4 l0 = *(const u16x4*)p0, h0 = *(const u16x4*)(p0 + 4);
            u16x4 l1 = *(const u16x4*)(p0 + 32), h1 = *(const u16x4*)(p0 + 36);
#pragma unroll
            for (int z = 0; z < 4; z++) { b0[z] = (short)l0[z]; b0[z+4] = (short)h0[z]; b1[z] = (short)l1[z]; b1[z+4] = (short)h1[z]; }
        }
#pragma unroll
        for (int mt = 0; mt < 4; mt++) {
            f32x4 acc = {0.f, 0.f, 0.f, 0.f};
            acc = __builtin_amdgcn_mfma_f32_16x16x32_bf16(af[mt][0], b0, acc, 0, 0, 0);
            acc = __builtin_amdgcn_mfma_f32_16x16x32_bf16(af[mt][1], b1, acc, 0, 0, 0);
            cc4[mt][nt] = acc;
        }
    }

    float bs[4] = {0.f, 0.f, 0.f, 0.f}, bq[4] = {0.f, 0.f, 0.f, 0.f};
#pragma unroll
    for (int mt = 0; mt < 4; mt++) {
        int row = r0 + w * 4 + mt;
        int gx[4];
#pragma unroll
        for (int r = 0; r < 4; r++) gx[r] = sidx[w * 64 + mt * 16 + quad * 4 + r];
#pragma unroll
        for (int nt = 0; nt < 4; nt++) {
            int c = nt * 16 + col;
            f32x4 a = cc4[mt][nt];
            float mx = fmaxf(fmaxf(a[0], a[1]), fmaxf(a[2], a[3]));
            mx = fmaxf(mx, __shfl_xor(mx, 16, 64));
            mx = fmaxf(mx, __shfl_xor(mx, 32, 64));
            float es = 0.f, ws = 0.f;
#pragma unroll
            for (int r = 0; r < 4; r++) {
                float e = __expf(a[r] - mx);
                float vv = Vf[gx[r] * 64 + c] + pos[mt][nt][r];
                es += e;
                ws = fmaf(e, vv, ws);
            }
            es += __shfl_xor(es, 16, 64); es += __shfl_xor(es, 32, 64);
            ws += __shfl_xor(ws, 16, 64); ws += __shfl_xor(ws, 32, 64);
            if (quad == 0) {
                float v = ws / es + feats[row * 64 + c];
                res[row * 64 + c] = v;
                bs[nt] += v;
                bq[nt] = fmaf(v, v, bq[nt]);
            }
        }
    }

    __syncthreads();
    float* fbuf = (float*)sA;
    if (quad == 0) {
#pragma unroll
        for (int nt = 0; nt < 4; nt++) {
            int c = nt * 16 + col;
            fbuf[w * 64 + c] = bs[nt];
            fbuf[256 + w * 64 + c] = bq[nt];
        }
    }
    __syncthreads();
    if (tid < 64) {
        float s = fbuf[tid] + fbuf[64 + tid] + fbuf[128 + tid] + fbuf[192 + tid];
        atomicAdd(&accum[tid], s);
    } else if (tid < 128) {
        int c = tid - 64;
        float q = fbuf[256 + c] + fbuf[320 + c] + fbuf[384 + c] + fbuf[448 + c];
        atomicAdd(&accum[64 + c], q);
    }
}

// ---------------- batchnorm apply + fp32 output ----------------
__global__ __launch_bounds__(256) void norm_kernel(const float* __restrict__ res,
                                                   const float* __restrict__ accum,
                                                   const float* __restrict__ bng,
                                                   const float* __restrict__ bnb,
                                                   float* __restrict__ out) {
    int i = blockIdx.x * 256 + threadIdx.x;
    int c = i & 63;
    float mean = accum[c] * (1.f / 16384.f);
    float var = accum[64 + c] * (1.f / 16384.f) - mean * mean;
    float sc = rsqrtf(var + 1e-5f) * bng[c];
    out[i] = fmaf(res[i] - mean, sc, bnb[c]);
}

extern "C" void kernel_launch(void* const* d_in, const int* in_sizes, int n_in,
                              void* d_out, int out_size, void* d_ws, size_t ws_size,
                              hipStream_t stream) {
    const float* xyz  = (const float*)d_in[0];
    const float* feats = (const float*)d_in[1];
    const float* w_qs = (const float*)d_in[2];
    const float* w_ks = (const float*)d_in[3];
    const float* w_vs = (const float*)d_in[4];
    const float* dw1 = (const float*)d_in[5];
    const float* db1 = (const float*)d_in[6];
    const float* dw2 = (const float*)d_in[7];
    const float* db2 = (const float*)d_in[8];
    const float* gw1 = (const float*)d_in[9];
    const float* gb1 = (const float*)d_in[10];
    const float* gw2 = (const float*)d_in[11];
    const float* bng = (const float*)d_in[13];
    const float* bnb = (const float*)d_in[14];

    char* ws = (char*)d_ws;
    float4* xyz4 = (float4*)ws;                       // 256 KB
    int* knn    = (int*)(ws + 262144);                // 1 MB
    float* Q    = (float*)(ws + 1310720);             // 4 MB
    float* Kf   = (float*)(ws + 5505024);             // 4 MB
    float* Vf   = (float*)(ws + 9699328);             // 4 MB
    float* res  = (float*)(ws + 13893632);            // 4 MB
    float* accum = (float*)(ws + 18087936);           // 512 B

    hipMemsetAsync(accum, 0, 512, stream);
    pack_xyz<<<64, 256, 0, stream>>>(xyz, xyz4);
    knn_kernel<<<2048, 256, 0, stream>>>(xyz4, knn);
    qkv_mfma<<<256, 256, 0, stream>>>(feats, w_qs, w_ks, w_vs, Q, Kf, Vf);
    attn_mfma<<<1024, 256, 0, stream>>>(xyz4, knn, Q, Kf, Vf, feats,
                                        dw1, db1, dw2, db2, gw1, gb1, gw2, res, accum);
    norm_kernel<<<4096, 256, 0, stream>>>(res, accum, bng, bnb, (float*)d_out);
}

// Round 14
// 264.278 us; speedup vs baseline: 1.0786x; 1.0786x over previous
//
#include <hip/hip_runtime.h>
#include <hip/hip_bf16.h>

#define BN 16384
#define NPTS 8192
#define KNN 16

typedef __attribute__((ext_vector_type(8))) short bf16x8;
typedef __attribute__((ext_vector_type(4))) float f32x4;

static __device__ __forceinline__ unsigned short f2bf(float f) {
    union { float f; unsigned u; } v; v.f = f;
    unsigned r = v.u + 0x7fffu + ((v.u >> 16) & 1u);
    return (unsigned short)(r >> 16);
}

static __device__ __forceinline__ float rfl(float v) {
    return __int_as_float(__builtin_amdgcn_readfirstlane(__float_as_int(v)));
}

// ---------------- pack xyz -> float4(x,y,z,|x|^2) ----------------
__global__ __launch_bounds__(256) void pack_xyz(const float* __restrict__ xyz,
                                                float4* __restrict__ xyz4) {
    int i = blockIdx.x * 256 + threadIdx.x;
    if (i < BN) {
        float x = xyz[i * 3 + 0], y = xyz[i * 3 + 1], z = xyz[i * 3 + 2];
        xyz4[i] = make_float4(x, y, z, x * x + y * y + z * z);
    }
}

// ---------------- weight prep: transpose + bf16, frag-ready global layout ----
// out[mat][n*64 + k] = bf16(W[k*64 + n]); B-frag = 16B at n*128B + quad*16B (+64B).
__global__ __launch_bounds__(256) void prep_w(const float* __restrict__ wq,
                                              const float* __restrict__ wk,
                                              const float* __restrict__ wv,
                                              const float* __restrict__ dw2,
                                              const float* __restrict__ gw1,
                                              const float* __restrict__ gw2,
                                              unsigned short* __restrict__ out) {
    const float* srcs[6] = {wq, wk, wv, dw2, gw1, gw2};
    const float* src = srcs[blockIdx.x];
    unsigned short* dst = out + blockIdx.x * 4096;
    for (int i = threadIdx.x; i < 4096; i += 256) {
        int k = i >> 6, n = i & 63;
        dst[n * 64 + k] = f2bf(src[i]);
    }
}

// ---------------- KNN (r10 known-good: 109us; r11/r13 variants regressed) ----
__global__ __launch_bounds__(256, 8) void knn_kernel(const float4* __restrict__ xyz4,
                                                     int* __restrict__ knn_idx) {
    __shared__ float wmaxs[4][8];
    __shared__ int   cnt[8];
    __shared__ float ckey[8 * 256];
    __shared__ int   cidx[8 * 256];
    int tid = threadIdx.x, lane = tid & 63, w = tid >> 6;
    int r0 = blockIdx.x * 8;
    int b = r0 >> 13;
    const float4* __restrict__ base = xyz4 + b * NPTS;

    float qx[8], qy[8], qz[8], minv[8];
#pragma unroll
    for (int rr = 0; rr < 8; rr++) {
        float4 q = xyz4[r0 + rr];
        qx[rr] = -2.f * q.x; qy[rr] = -2.f * q.y; qz[rr] = -2.f * q.z;
        minv[rr] = 3e38f;
    }
    if (tid < 8) cnt[tid] = 0;

#pragma unroll 4
    for (int i = 0; i < 32; i++) {
        float4 c = base[tid + (i << 8)];
#pragma unroll
        for (int rr = 0; rr < 8; rr++) {
            float d = fmaf(qx[rr], c.x, fmaf(qy[rr], c.y, fmaf(qz[rr], c.z, c.w)));
            minv[rr] = fminf(minv[rr], d);
        }
    }

#pragma unroll
    for (int rr = 0; rr < 8; rr++) {
        float v = minv[rr];
        v = fminf(v, __shfl_xor(v, 1, 64));
        v = fminf(v, __shfl_xor(v, 2, 64));
        v = fminf(v, __shfl_xor(v, 4, 64));
        v = fminf(v, __shfl_xor(v, 8, 64));
        v = fmaxf(v, __shfl_xor(v, 16, 64));
        v = fmaxf(v, __shfl_xor(v, 32, 64));
        if (lane == 0) wmaxs[w][rr] = v;
    }
    __syncthreads();
    float T[8];
#pragma unroll
    for (int rr = 0; rr < 8; rr++)
        T[rr] = rfl(fmaxf(fmaxf(wmaxs[0][rr], wmaxs[1][rr]),
                          fmaxf(wmaxs[2][rr], wmaxs[3][rr])));

#pragma unroll 2
    for (int i = 0; i < 32; i++) {
        float4 c = base[tid + (i << 8)];
#pragma unroll
        for (int rr = 0; rr < 8; rr++) {
            float d = fmaf(qx[rr], c.x, fmaf(qy[rr], c.y, fmaf(qz[rr], c.z, c.w)));
            if (d <= T[rr]) {
                int p = atomicAdd(&cnt[rr], 1);
                if (p < 256) { ckey[rr * 256 + p] = d; cidx[rr * 256 + p] = tid + (i << 8); }
            }
        }
    }
    __syncthreads();

    for (int rr = w; rr < 8; rr += 4) {
        int cc = min(cnt[rr], 256);
        for (int s = lane; s < cc; s += 64) {
            float myk = ckey[rr * 256 + s]; int myi = cidx[rr * 256 + s];
            int rank = 0;
            for (int j2 = 0; j2 < cc; j2++) {
                float kj = ckey[rr * 256 + j2]; int ij = cidx[rr * 256 + j2];
                rank += (kj < myk || (kj == myk && ij < myi)) ? 1 : 0;
            }
            if (rank < 16) knn_idx[(r0 + rr) * 16 + rank] = myi;
        }
    }
}

// ---------------- Q/K/V projections via MFMA (weights from global bf16) ------
__global__ __launch_bounds__(256) void qkv_mfma(const float* __restrict__ feats,
                                                const unsigned short* __restrict__ wbf,
                                                float* __restrict__ Q,
                                                float* __restrict__ Kf,
                                                float* __restrict__ Vf) {
    int tid = threadIdx.x;
    int w = tid >> 6, lane = tid & 63, quad = lane >> 4, col = lane & 15;

    int row0 = blockIdx.x * 64 + w * 16;
    bf16x8 a0, a1;
    {
        const float* fp = feats + (row0 + col) * 64 + quad * 8;
        float4 x0 = *(const float4*)fp,        x1 = *(const float4*)(fp + 4);
        float4 x2 = *(const float4*)(fp + 32), x3 = *(const float4*)(fp + 36);
        a0[0] = (short)f2bf(x0.x); a0[1] = (short)f2bf(x0.y); a0[2] = (short)f2bf(x0.z); a0[3] = (short)f2bf(x0.w);
        a0[4] = (short)f2bf(x1.x); a0[5] = (short)f2bf(x1.y); a0[6] = (short)f2bf(x1.z); a0[7] = (short)f2bf(x1.w);
        a1[0] = (short)f2bf(x2.x); a1[1] = (short)f2bf(x2.y); a1[2] = (short)f2bf(x2.z); a1[3] = (short)f2bf(x2.w);
        a1[4] = (short)f2bf(x3.x); a1[5] = (short)f2bf(x3.y); a1[6] = (short)f2bf(x3.z); a1[7] = (short)f2bf(x3.w);
    }

    float* outs[3] = {Q, Kf, Vf};
#pragma unroll
    for (int mat = 0; mat < 3; mat++) {
        float* out = outs[mat];
#pragma unroll
        for (int nt = 0; nt < 4; nt++) {
            const unsigned short* p0 = wbf + mat * 4096 + (nt * 16 + col) * 64 + quad * 8;
            bf16x8 b0 = *(const bf16x8*)p0;
            bf16x8 b1 = *(const bf16x8*)(p0 + 32);
            f32x4 acc = {0.f, 0.f, 0.f, 0.f};
            acc = __builtin_amdgcn_mfma_f32_16x16x32_bf16(a0, b0, acc, 0, 0, 0);
            acc = __builtin_amdgcn_mfma_f32_16x16x32_bf16(a1, b1, acc, 0, 0, 0);
#pragma unroll
            for (int r = 0; r < 4; r++)
                out[(row0 + quad * 4 + r) * 64 + nt * 16 + col] = acc[r];
        }
    }
}

// ---------------- fused attention + BN partial sums ----------------
// Weights as B-frags straight from global bf16 (L1-resident 24KB) -> LDS 39KB
// -> 3 blocks/CU (was 2 at 64.5KB). One weight-staging loop and 26KB removed.
__global__ __launch_bounds__(256, 3) void attn_mfma(
    const float4* __restrict__ xyz4, const int* __restrict__ knn_idx,
    const float* __restrict__ Q, const float* __restrict__ Kf, const float* __restrict__ Vf,
    const float* __restrict__ feats, const unsigned short* __restrict__ wbf,
    const float* __restrict__ dw1, const float* __restrict__ db1,
    const float* __restrict__ db2, const float* __restrict__ gb1,
    float* __restrict__ res, float* __restrict__ accum) {
    __shared__ __align__(16) unsigned short sA[256 * 72];
    __shared__ int sidx[256];
    __shared__ float sdw1[256];

    int tid = threadIdx.x;
    int w = tid >> 6, lane = tid & 63, quad = lane >> 4, col = lane & 15;
    int r0 = blockIdx.x * 16;

    if (tid < 192) sdw1[tid] = dw1[tid];
    else sdw1[tid] = db1[tid - 192];
    {
        int brow = r0 + (tid >> 4);
        int b = brow >> 13;
        sidx[tid] = b * NPTS + knn_idx[brow * 16 + (tid & 15)];
    }
    __syncthreads();

    // H1 = relu(rel @ dw1 + db1), thread per m-row, bf16 into sA
    {
        int m = tid;
        int brow = r0 + (m >> 4);
        float4 p = xyz4[brow];
        float4 nb = xyz4[sidx[m]];
        float rx = p.x - nb.x, ry = p.y - nb.y, rz = p.z - nb.z;
        for (int c0 = 0; c0 < 64; c0 += 8) {
            bf16x8 v;
#pragma unroll
            for (int cc = 0; cc < 8; cc++) {
                int c = c0 + cc;
                float h = sdw1[192 + c] + rx * sdw1[c] + ry * sdw1[64 + c] + rz * sdw1[128 + c];
                v[cc] = (short)f2bf(fmaxf(h, 0.f));
            }
            *(bf16x8*)&sA[m * 72 + c0] = v;
        }
    }

    int m0 = w * 64;
    bf16x8 af[4][2];
    const unsigned short* wd2 = wbf + 3 * 4096;
    const unsigned short* wg1 = wbf + 4 * 4096;
    const unsigned short* wg2 = wbf + 5 * 4096;

    // GEMM2: pos = H1 @ dw2 + db2 (C-frags stay in registers)
#pragma unroll
    for (int mt = 0; mt < 4; mt++)
#pragma unroll
        for (int k2 = 0; k2 < 2; k2++)
            af[mt][k2] = *(const bf16x8*)&sA[(m0 + mt * 16 + col) * 72 + quad * 8 + k2 * 32];

    f32x4 pos[4][4];
#pragma unroll
    for (int nt = 0; nt < 4; nt++) {
        float bias = db2[nt * 16 + col];
        const unsigned short* p0 = wd2 + (nt * 16 + col) * 64 + quad * 8;
        bf16x8 b0 = *(const bf16x8*)p0;
        bf16x8 b1 = *(const bf16x8*)(p0 + 32);
#pragma unroll
        for (int mt = 0; mt < 4; mt++) {
            f32x4 acc = {bias, bias, bias, bias};
            acc = __builtin_amdgcn_mfma_f32_16x16x32_bf16(af[mt][0], b0, acc, 0, 0, 0);
            acc = __builtin_amdgcn_mfma_f32_16x16x32_bf16(af[mt][1], b1, acc, 0, 0, 0);
            pos[mt][nt] = acc;
        }
    }

    // tvec = q - k_gathered + pos -> bf16 into sA (wave-private rows)
#pragma unroll
    for (int mt = 0; mt < 4; mt++) {
        int row = r0 + w * 4 + mt;
        int gx[4];
#pragma unroll
        for (int r = 0; r < 4; r++) gx[r] = sidx[w * 64 + mt * 16 + quad * 4 + r];
#pragma unroll
        for (int nt = 0; nt < 4; nt++) {
            int c = nt * 16 + col;
            float qv = Q[row * 64 + c];
#pragma unroll
            for (int r = 0; r < 4; r++) {
                float tv = qv - Kf[gx[r] * 64 + c] + pos[mt][nt][r];
                sA[(m0 + mt * 16 + quad * 4 + r) * 72 + c] = f2bf(tv);
            }
        }
    }

    // GEMM3: h2 = relu(tvec @ gw1 + gb1) -> bf16 into sA
#pragma unroll
    for (int mt = 0; mt < 4; mt++)
#pragma unroll
        for (int k2 = 0; k2 < 2; k2++)
            af[mt][k2] = *(const bf16x8*)&sA[(m0 + mt * 16 + col) * 72 + quad * 8 + k2 * 32];

    f32x4 cc4[4][4];
#pragma unroll
    for (int nt = 0; nt < 4; nt++) {
        float bias = gb1[nt * 16 + col];
        const unsigned short* p0 = wg1 + (nt * 16 + col) * 64 + quad * 8;
        bf16x8 b0 = *(const bf16x8*)p0;
        bf16x8 b1 = *(const bf16x8*)(p0 + 32);
#pragma unroll
        for (int mt = 0; mt < 4; mt++) {
            f32x4 acc = {bias, bias, bias, bias};
            acc = __builtin_amdgcn_mfma_f32_16x16x32_bf16(af[mt][0], b0, acc, 0, 0, 0);
            acc = __builtin_amdgcn_mfma_f32_16x16x32_bf16(af[mt][1], b1, acc, 0, 0, 0);
            cc4[mt][nt] = acc;
        }
    }
#pragma unroll
    for (int mt = 0; mt < 4; mt++)
#pragma unroll
        for (int nt = 0; nt < 4; nt++)
#pragma unroll
            for (int r = 0; r < 4; r++)
                sA[(m0 + mt * 16 + quad * 4 + r) * 72 + nt * 16 + col] = f2bf(fmaxf(cc4[mt][nt][r], 0.f));

    // GEMM4: attn = h2 @ gw2 (gb2 cancels in softmax)
#pragma unroll
    for (int mt = 0; mt < 4; mt++)
#pragma unroll
        for (int k2 = 0; k2 < 2; k2++)
            af[mt][k2] = *(const bf16x8*)&sA[(m0 + mt * 16 + col) * 72 + quad * 8 + k2 * 32];

#pragma unroll
    for (int nt = 0; nt < 4; nt++) {
        const unsigned short* p0 = wg2 + (nt * 16 + col) * 64 + quad * 8;
        bf16x8 b0 = *(const bf16x8*)p0;
        bf16x8 b1 = *(const bf16x8*)(p0 + 32);
#pragma unroll
        for (int mt = 0; mt < 4; mt++) {
            f32x4 acc = {0.f, 0.f, 0.f, 0.f};
            acc = __builtin_amdgcn_mfma_f32_16x16x32_bf16(af[mt][0], b0, acc, 0, 0, 0);
            acc = __builtin_amdgcn_mfma_f32_16x16x32_bf16(af[mt][1], b1, acc, 0, 0, 0);
            cc4[mt][nt] = acc;
        }
    }

    // softmax over 16 neighbors + weighted sum + residual + BN partials
    float bs[4] = {0.f, 0.f, 0.f, 0.f}, bq[4] = {0.f, 0.f, 0.f, 0.f};
#pragma unroll
    for (int mt = 0; mt < 4; mt++) {
        int row = r0 + w * 4 + mt;
        int gx[4];
#pragma unroll
        for (int r = 0; r < 4; r++) gx[r] = sidx[w * 64 + mt * 16 + quad * 4 + r];
#pragma unroll
        for (int nt = 0; nt < 4; nt++) {
            int c = nt * 16 + col;
            f32x4 a = cc4[mt][nt];
            float mx = fmaxf(fmaxf(a[0], a[1]), fmaxf(a[2], a[3]));
            mx = fmaxf(mx, __shfl_xor(mx, 16, 64));
            mx = fmaxf(mx, __shfl_xor(mx, 32, 64));
            float es = 0.f, ws = 0.f;
#pragma unroll
            for (int r = 0; r < 4; r++) {
                float e = __expf(a[r] - mx);
                float vv = Vf[gx[r] * 64 + c] + pos[mt][nt][r];
                es += e;
                ws = fmaf(e, vv, ws);
            }
            es += __shfl_xor(es, 16, 64); es += __shfl_xor(es, 32, 64);
            ws += __shfl_xor(ws, 16, 64); ws += __shfl_xor(ws, 32, 64);
            if (quad == 0) {
                float v = ws / es + feats[row * 64 + c];
                res[row * 64 + c] = v;
                bs[nt] += v;
                bq[nt] = fmaf(v, v, bq[nt]);
            }
        }
    }

    __syncthreads();
    float* fbuf = (float*)sA;
    if (quad == 0) {
#pragma unroll
        for (int nt = 0; nt < 4; nt++) {
            int c = nt * 16 + col;
            fbuf[w * 64 + c] = bs[nt];
            fbuf[256 + w * 64 + c] = bq[nt];
        }
    }
    __syncthreads();
    if (tid < 64) {
        float s = fbuf[tid] + fbuf[64 + tid] + fbuf[128 + tid] + fbuf[192 + tid];
        atomicAdd(&accum[tid], s);
    } else if (tid < 128) {
        int c = tid - 64;
        float q = fbuf[256 + c] + fbuf[320 + c] + fbuf[384 + c] + fbuf[448 + c];
        atomicAdd(&accum[64 + c], q);
    }
}

// ---------------- batchnorm apply + fp32 output ----------------
__global__ __launch_bounds__(256) void norm_kernel(const float* __restrict__ res,
                                                   const float* __restrict__ accum,
                                                   const float* __restrict__ bng,
                                                   const float* __restrict__ bnb,
                                                   float* __restrict__ out) {
    int i = blockIdx.x * 256 + threadIdx.x;
    int c = i & 63;
    float mean = accum[c] * (1.f / 16384.f);
    float var = accum[64 + c] * (1.f / 16384.f) - mean * mean;
    float sc = rsqrtf(var + 1e-5f) * bng[c];
    out[i] = fmaf(res[i] - mean, sc, bnb[c]);
}

extern "C" void kernel_launch(void* const* d_in, const int* in_sizes, int n_in,
                              void* d_out, int out_size, void* d_ws, size_t ws_size,
                              hipStream_t stream) {
    const float* xyz  = (const float*)d_in[0];
    const float* feats = (const float*)d_in[1];
    const float* w_qs = (const float*)d_in[2];
    const float* w_ks = (const float*)d_in[3];
    const float* w_vs = (const float*)d_in[4];
    const float* dw1 = (const float*)d_in[5];
    const float* db1 = (const float*)d_in[6];
    const float* dw2 = (const float*)d_in[7];
    const float* db2 = (const float*)d_in[8];
    const float* gw1 = (const float*)d_in[9];
    const float* gb1 = (const float*)d_in[10];
    const float* gw2 = (const float*)d_in[11];
    const float* bng = (const float*)d_in[13];
    const float* bnb = (const float*)d_in[14];

    char* ws = (char*)d_ws;
    float4* xyz4 = (float4*)ws;                        // 256 KB
    int* knn    = (int*)(ws + 262144);                 // 1 MB
    float* Q    = (float*)(ws + 1310720);              // 4 MB
    float* Kf   = (float*)(ws + 5505024);              // 4 MB
    float* Vf   = (float*)(ws + 9699328);              // 4 MB
    float* res  = (float*)(ws + 13893632);             // 4 MB
    float* accum = (float*)(ws + 18087936);            // 512 B
    unsigned short* wbf = (unsigned short*)(ws + 18088448); // 48 KB bf16 weights

    hipMemsetAsync(accum, 0, 512, stream);
    prep_w<<<6, 256, 0, stream>>>(w_qs, w_ks, w_vs, dw2, gw1, gw2, wbf);
    pack_xyz<<<64, 256, 0, stream>>>(xyz, xyz4);
    knn_kernel<<<2048, 256, 0, stream>>>(xyz4, knn);
    qkv_mfma<<<256, 256, 0, stream>>>(feats, wbf, Q, Kf, Vf);
    attn_mfma<<<1024, 256, 0, stream>>>(xyz4, knn, Q, Kf, Vf, feats, wbf,
                                        dw1, db1, db2, gb1, res, accum);
    norm_kernel<<<4096, 256, 0, stream>>>(res, accum, bng, bnb, (float*)d_out);
}

// Round 15
// 253.506 us; speedup vs baseline: 1.1244x; 1.0425x over previous
//
#include <hip/hip_runtime.h>
#include <hip/hip_bf16.h>

#define BN 16384
#define NPTS 8192
#define KNN 16

typedef __attribute__((ext_vector_type(8))) short bf16x8;
typedef __attribute__((ext_vector_type(4))) float f32x4;
typedef __attribute__((ext_vector_type(4))) unsigned short u16x4;

static __device__ __forceinline__ unsigned short f2bf(float f) {
    union { float f; unsigned u; } v; v.f = f;
    unsigned r = v.u + 0x7fffu + ((v.u >> 16) & 1u);
    return (unsigned short)(r >> 16);
}

static __device__ __forceinline__ float rfl(float v) {
    return __int_as_float(__builtin_amdgcn_readfirstlane(__float_as_int(v)));
}

// ---------------- pack xyz + prep qkv weights (fused; role by blockIdx) ------
// blocks 0..63: xyz -> float4(x,y,z,|x|^2). blocks 64..66: transpose+bf16 one
// of wq/wk/wv into frag-ready layout out[mat][n*64+k].
__global__ __launch_bounds__(256) void pack_prep(const float* __restrict__ xyz,
                                                 float4* __restrict__ xyz4,
                                                 const float* __restrict__ wq,
                                                 const float* __restrict__ wk,
                                                 const float* __restrict__ wv,
                                                 unsigned short* __restrict__ wbf) {
    if (blockIdx.x < 64) {
        int i = blockIdx.x * 256 + threadIdx.x;
        float x = xyz[i * 3 + 0], y = xyz[i * 3 + 1], z = xyz[i * 3 + 2];
        xyz4[i] = make_float4(x, y, z, x * x + y * y + z * z);
    } else {
        int mat = blockIdx.x - 64;
        const float* src = (mat == 0) ? wq : (mat == 1) ? wk : wv;
        unsigned short* dst = wbf + mat * 4096;
        for (int i = threadIdx.x; i < 4096; i += 256) {
            int k = i >> 6, n = i & 63;
            dst[n * 64 + k] = f2bf(src[i]);
        }
    }
}

// ---------------- fused KNN + QKV (role by blockIdx) ----------------
// blocks 0..255: qkv MFMA (64 rows each, weights from global bf16).
// blocks 256..2303: knn (r10 known-good structure, 8 rows each).
// Union resources: LDS 16.9KB (knn arrays), VGPR <=64 both paths -> 8 blk/CU.
__global__ __launch_bounds__(256, 8) void knnqkv_kernel(
    const float4* __restrict__ xyz4, int* __restrict__ knn_idx,
    const float* __restrict__ feats, const unsigned short* __restrict__ wbf,
    float* __restrict__ Q, float* __restrict__ Kf, float* __restrict__ Vf) {
    __shared__ float wmaxs[4][8];
    __shared__ int   cnt[8];
    __shared__ float ckey[8 * 256];
    __shared__ int   cidx[8 * 256];
    int tid = threadIdx.x, lane = tid & 63, w = tid >> 6;

    if (blockIdx.x < 256) {
        // ---------------- QKV path ----------------
        int quad = lane >> 4, col = lane & 15;
        int row0 = blockIdx.x * 64 + w * 16;
        bf16x8 a0, a1;
        {
            const float* fp = feats + (row0 + col) * 64 + quad * 8;
            float4 x0 = *(const float4*)fp,        x1 = *(const float4*)(fp + 4);
            float4 x2 = *(const float4*)(fp + 32), x3 = *(const float4*)(fp + 36);
            a0[0] = (short)f2bf(x0.x); a0[1] = (short)f2bf(x0.y); a0[2] = (short)f2bf(x0.z); a0[3] = (short)f2bf(x0.w);
            a0[4] = (short)f2bf(x1.x); a0[5] = (short)f2bf(x1.y); a0[6] = (short)f2bf(x1.z); a0[7] = (short)f2bf(x1.w);
            a1[0] = (short)f2bf(x2.x); a1[1] = (short)f2bf(x2.y); a1[2] = (short)f2bf(x2.z); a1[3] = (short)f2bf(x2.w);
            a1[4] = (short)f2bf(x3.x); a1[5] = (short)f2bf(x3.y); a1[6] = (short)f2bf(x3.z); a1[7] = (short)f2bf(x3.w);
        }
        float* outs[3] = {Q, Kf, Vf};
#pragma unroll
        for (int mat = 0; mat < 3; mat++) {
            float* out = outs[mat];
#pragma unroll
            for (int nt = 0; nt < 4; nt++) {
                const unsigned short* p0 = wbf + mat * 4096 + (nt * 16 + col) * 64 + quad * 8;
                bf16x8 b0 = *(const bf16x8*)p0;
                bf16x8 b1 = *(const bf16x8*)(p0 + 32);
                f32x4 acc = {0.f, 0.f, 0.f, 0.f};
                acc = __builtin_amdgcn_mfma_f32_16x16x32_bf16(a0, b0, acc, 0, 0, 0);
                acc = __builtin_amdgcn_mfma_f32_16x16x32_bf16(a1, b1, acc, 0, 0, 0);
#pragma unroll
                for (int r = 0; r < 4; r++)
                    out[(row0 + quad * 4 + r) * 64 + nt * 16 + col] = acc[r];
            }
        }
        return;
    }

    // ---------------- KNN path (r10 structure) ----------------
    int r0 = (blockIdx.x - 256) * 8;
    int b = r0 >> 13;
    const float4* __restrict__ base = xyz4 + b * NPTS;

    float qx[8], qy[8], qz[8], minv[8];
#pragma unroll
    for (int rr = 0; rr < 8; rr++) {
        float4 q = xyz4[r0 + rr];
        qx[rr] = -2.f * q.x; qy[rr] = -2.f * q.y; qz[rr] = -2.f * q.z;
        minv[rr] = 3e38f;
    }
    if (tid < 8) cnt[tid] = 0;

#pragma unroll 4
    for (int i = 0; i < 32; i++) {
        float4 c = base[tid + (i << 8)];
#pragma unroll
        for (int rr = 0; rr < 8; rr++) {
            float d = fmaf(qx[rr], c.x, fmaf(qy[rr], c.y, fmaf(qz[rr], c.z, c.w)));
            minv[rr] = fminf(minv[rr], d);
        }
    }

#pragma unroll
    for (int rr = 0; rr < 8; rr++) {
        float v = minv[rr];
        v = fminf(v, __shfl_xor(v, 1, 64));
        v = fminf(v, __shfl_xor(v, 2, 64));
        v = fminf(v, __shfl_xor(v, 4, 64));
        v = fminf(v, __shfl_xor(v, 8, 64));
        v = fmaxf(v, __shfl_xor(v, 16, 64));
        v = fmaxf(v, __shfl_xor(v, 32, 64));
        if (lane == 0) wmaxs[w][rr] = v;
    }
    __syncthreads();
    float T[8];
#pragma unroll
    for (int rr = 0; rr < 8; rr++)
        T[rr] = rfl(fmaxf(fmaxf(wmaxs[0][rr], wmaxs[1][rr]),
                          fmaxf(wmaxs[2][rr], wmaxs[3][rr])));

#pragma unroll 2
    for (int i = 0; i < 32; i++) {
        float4 c = base[tid + (i << 8)];
#pragma unroll
        for (int rr = 0; rr < 8; rr++) {
            float d = fmaf(qx[rr], c.x, fmaf(qy[rr], c.y, fmaf(qz[rr], c.z, c.w)));
            if (d <= T[rr]) {
                int p = atomicAdd(&cnt[rr], 1);
                if (p < 256) { ckey[rr * 256 + p] = d; cidx[rr * 256 + p] = tid + (i << 8); }
            }
        }
    }
    __syncthreads();

    for (int rr = w; rr < 8; rr += 4) {
        int cc = min(cnt[rr], 256);
        for (int s = lane; s < cc; s += 64) {
            float myk = ckey[rr * 256 + s]; int myi = cidx[rr * 256 + s];
            int rank = 0;
            for (int j2 = 0; j2 < cc; j2++) {
                float kj = ckey[rr * 256 + j2]; int ij = cidx[rr * 256 + j2];
                rank += (kj < myk || (kj == myk && ij < myi)) ? 1 : 0;
            }
            if (rank < 16) knn_idx[(r0 + rr) * 16 + rank] = myi;
        }
    }
}

// ---------------- fused attention + BN partial sums (r12 known-good) ---------
__global__ __launch_bounds__(256, 2) void attn_mfma(
    const float4* __restrict__ xyz4, const int* __restrict__ knn_idx,
    const float* __restrict__ Q, const float* __restrict__ Kf, const float* __restrict__ Vf,
    const float* __restrict__ feats,
    const float* __restrict__ dw1, const float* __restrict__ db1,
    const float* __restrict__ dw2, const float* __restrict__ db2,
    const float* __restrict__ gw1, const float* __restrict__ gb1,
    const float* __restrict__ gw2,
    float* __restrict__ res, float* __restrict__ accum) {
    __shared__ __align__(16) unsigned short sWd2[64 * 68];
    __shared__ __align__(16) unsigned short sWg1[64 * 68];
    __shared__ __align__(16) unsigned short sWg2[64 * 68];
    __shared__ __align__(16) unsigned short sA[256 * 72];
    __shared__ int sidx[256];
    __shared__ float sdw1[256];

    int tid = threadIdx.x;
    int w = tid >> 6, lane = tid & 63, quad = lane >> 4, col = lane & 15;
    int r0 = blockIdx.x * 16;

    for (int i = tid; i < 4096; i += 256) {
        int e = i >> 6, c = i & 63;
        sWd2[c * 68 + e] = f2bf(dw2[i]);
        sWg1[c * 68 + e] = f2bf(gw1[i]);
        sWg2[c * 68 + e] = f2bf(gw2[i]);
    }
    if (tid < 192) sdw1[tid] = dw1[tid];
    else sdw1[tid] = db1[tid - 192];
    {
        int brow = r0 + (tid >> 4);
        int b = brow >> 13;
        sidx[tid] = b * NPTS + knn_idx[brow * 16 + (tid & 15)];
    }
    __syncthreads();

    {
        int m = tid;
        int brow = r0 + (m >> 4);
        float4 p = xyz4[brow];
        float4 nb = xyz4[sidx[m]];
        float rx = p.x - nb.x, ry = p.y - nb.y, rz = p.z - nb.z;
        for (int c0 = 0; c0 < 64; c0 += 8) {
            bf16x8 v;
#pragma unroll
            for (int cc = 0; cc < 8; cc++) {
                int c = c0 + cc;
                float h = sdw1[192 + c] + rx * sdw1[c] + ry * sdw1[64 + c] + rz * sdw1[128 + c];
                v[cc] = (short)f2bf(fmaxf(h, 0.f));
            }
            *(bf16x8*)&sA[m * 72 + c0] = v;
        }
    }

    int m0 = w * 64;
    bf16x8 af[4][2];

#pragma unroll
    for (int mt = 0; mt < 4; mt++)
#pragma unroll
        for (int k2 = 0; k2 < 2; k2++)
            af[mt][k2] = *(const bf16x8*)&sA[(m0 + mt * 16 + col) * 72 + quad * 8 + k2 * 32];

    f32x4 pos[4][4];
#pragma unroll
    for (int nt = 0; nt < 4; nt++) {
        float bias = db2[nt * 16 + col];
        bf16x8 b0, b1;
        {
            const unsigned short* p0 = &sWd2[(nt * 16 + col) * 68 + quad * 8];
            u16x4 l0 = *(const u16x4*)p0, h0 = *(const u16x4*)(p0 + 4);
            u16x4 l1 = *(const u16x4*)(p0 + 32), h1 = *(const u16x4*)(p0 + 36);
#pragma unroll
            for (int z = 0; z < 4; z++) { b0[z] = (short)l0[z]; b0[z+4] = (short)h0[z]; b1[z] = (short)l1[z]; b1[z+4] = (short)h1[z]; }
        }
#pragma unroll
        for (int mt = 0; mt < 4; mt++) {
            f32x4 acc = {bias, bias, bias, bias};
            acc = __builtin_amdgcn_mfma_f32_16x16x32_bf16(af[mt][0], b0, acc, 0, 0, 0);
            acc = __builtin_amdgcn_mfma_f32_16x16x32_bf16(af[mt][1], b1, acc, 0, 0, 0);
            pos[mt][nt] = acc;
        }
    }

#pragma unroll
    for (int mt = 0; mt < 4; mt++) {
        int row = r0 + w * 4 + mt;
        int gx[4];
#pragma unroll
        for (int r = 0; r < 4; r++) gx[r] = sidx[w * 64 + mt * 16 + quad * 4 + r];
#pragma unroll
        for (int nt = 0; nt < 4; nt++) {
            int c = nt * 16 + col;
            float qv = Q[row * 64 + c];
#pragma unroll
            for (int r = 0; r < 4; r++) {
                float tv = qv - Kf[gx[r] * 64 + c] + pos[mt][nt][r];
                sA[(m0 + mt * 16 + quad * 4 + r) * 72 + c] = f2bf(tv);
            }
        }
    }

#pragma unroll
    for (int mt = 0; mt < 4; mt++)
#pragma unroll
        for (int k2 = 0; k2 < 2; k2++)
            af[mt][k2] = *(const bf16x8*)&sA[(m0 + mt * 16 + col) * 72 + quad * 8 + k2 * 32];

    f32x4 cc4[4][4];
#pragma unroll
    for (int nt = 0; nt < 4; nt++) {
        float bias = gb1[nt * 16 + col];
        bf16x8 b0, b1;
        {
            const unsigned short* p0 = &sWg1[(nt * 16 + col) * 68 + quad * 8];
            u16x4 l0 = *(const u16x4*)p0, h0 = *(const u16x4*)(p0 + 4);
            u16x4 l1 = *(const u16x4*)(p0 + 32), h1 = *(const u16x4*)(p0 + 36);
#pragma unroll
            for (int z = 0; z < 4; z++) { b0[z] = (short)l0[z]; b0[z+4] = (short)h0[z]; b1[z] = (short)l1[z]; b1[z+4] = (short)h1[z]; }
        }
#pragma unroll
        for (int mt = 0; mt < 4; mt++) {
            f32x4 acc = {bias, bias, bias, bias};
            acc = __builtin_amdgcn_mfma_f32_16x16x32_bf16(af[mt][0], b0, acc, 0, 0, 0);
            acc = __builtin_amdgcn_mfma_f32_16x16x32_bf16(af[mt][1], b1, acc, 0, 0, 0);
            cc4[mt][nt] = acc;
        }
    }
#pragma unroll
    for (int mt = 0; mt < 4; mt++)
#pragma unroll
        for (int nt = 0; nt < 4; nt++)
#pragma unroll
            for (int r = 0; r < 4; r++)
                sA[(m0 + mt * 16 + quad * 4 + r) * 72 + nt * 16 + col] = f2bf(fmaxf(cc4[mt][nt][r], 0.f));

#pragma unroll
    for (int mt = 0; mt < 4; mt++)
#pragma unroll
        for (int k2 = 0; k2 < 2; k2++)
            af[mt][k2] = *(const bf16x8*)&sA[(m0 + mt * 16 + col) * 72 + quad * 8 + k2 * 32];

#pragma unroll
    for (int nt = 0; nt < 4; nt++) {
        bf16x8 b0, b1;
        {
            const unsigned short* p0 = &sWg2[(nt * 16 + col) * 68 + quad * 8];
            u16x4 l0 = *(const u16x4*)p0, h0 = *(const u16x4*)(p0 + 4);
            u16x4 l1 = *(const u16x4*)(p0 + 32), h1 = *(const u16x4*)(p0 + 36);
#pragma unroll
            for (int z = 0; z < 4; z++) { b0[z] = (short)l0[z]; b0[z+4] = (short)h0[z]; b1[z] = (short)l1[z]; b1[z+4] = (short)h1[z]; }
        }
#pragma unroll
        for (int mt = 0; mt < 4; mt++) {
            f32x4 acc = {0.f, 0.f, 0.f, 0.f};
            acc = __builtin_amdgcn_mfma_f32_16x16x32_bf16(af[mt][0], b0, acc, 0, 0, 0);
            acc = __builtin_amdgcn_mfma_f32_16x16x32_bf16(af[mt][1], b1, acc, 0, 0, 0);
            cc4[mt][nt] = acc;
        }
    }

    float bs[4] = {0.f, 0.f, 0.f, 0.f}, bq[4] = {0.f, 0.f, 0.f, 0.f};
#pragma unroll
    for (int mt = 0; mt < 4; mt++) {
        int row = r0 + w * 4 + mt;
        int gx[4];
#pragma unroll
        for (int r = 0; r < 4; r++) gx[r] = sidx[w * 64 + mt * 16 + quad * 4 + r];
#pragma unroll
        for (int nt = 0; nt < 4; nt++) {
            int c = nt * 16 + col;
            f32x4 a = cc4[mt][nt];
            float mx = fmaxf(fmaxf(a[0], a[1]), fmaxf(a[2], a[3]));
            mx = fmaxf(mx, __shfl_xor(mx, 16, 64));
            mx = fmaxf(mx, __shfl_xor(mx, 32, 64));
            float es = 0.f, ws = 0.f;
#pragma unroll
            for (int r = 0; r < 4; r++) {
                float e = __expf(a[r] - mx);
                float vv = Vf[gx[r] * 64 + c] + pos[mt][nt][r];
                es += e;
                ws = fmaf(e, vv, ws);
            }
            es += __shfl_xor(es, 16, 64); es += __shfl_xor(es, 32, 64);
            ws += __shfl_xor(ws, 16, 64); ws += __shfl_xor(ws, 32, 64);
            if (quad == 0) {
                float v = ws / es + feats[row * 64 + c];
                res[row * 64 + c] = v;
                bs[nt] += v;
                bq[nt] = fmaf(v, v, bq[nt]);
            }
        }
    }

    __syncthreads();
    float* fbuf = (float*)sA;
    if (quad == 0) {
#pragma unroll
        for (int nt = 0; nt < 4; nt++) {
            int c = nt * 16 + col;
            fbuf[w * 64 + c] = bs[nt];
            fbuf[256 + w * 64 + c] = bq[nt];
        }
    }
    __syncthreads();
    if (tid < 64) {
        float s = fbuf[tid] + fbuf[64 + tid] + fbuf[128 + tid] + fbuf[192 + tid];
        atomicAdd(&accum[tid], s);
    } else if (tid < 128) {
        int c = tid - 64;
        float q = fbuf[256 + c] + fbuf[320 + c] + fbuf[384 + c] + fbuf[448 + c];
        atomicAdd(&accum[64 + c], q);
    }
}

// ---------------- batchnorm apply + fp32 output ----------------
__global__ __launch_bounds__(256) void norm_kernel(const float* __restrict__ res,
                                                   const float* __restrict__ accum,
                                                   const float* __restrict__ bng,
                                                   const float* __restrict__ bnb,
                                                   float* __restrict__ out) {
    int i = blockIdx.x * 256 + threadIdx.x;
    int c = i & 63;
    float mean = accum[c] * (1.f / 16384.f);
    float var = accum[64 + c] * (1.f / 16384.f) - mean * mean;
    float sc = rsqrtf(var + 1e-5f) * bng[c];
    out[i] = fmaf(res[i] - mean, sc, bnb[c]);
}

extern "C" void kernel_launch(void* const* d_in, const int* in_sizes, int n_in,
                              void* d_out, int out_size, void* d_ws, size_t ws_size,
                              hipStream_t stream) {
    const float* xyz  = (const float*)d_in[0];
    const float* feats = (const float*)d_in[1];
    const float* w_qs = (const float*)d_in[2];
    const float* w_ks = (const float*)d_in[3];
    const float* w_vs = (const float*)d_in[4];
    const float* dw1 = (const float*)d_in[5];
    const float* db1 = (const float*)d_in[6];
    const float* dw2 = (const float*)d_in[7];
    const float* db2 = (const float*)d_in[8];
    const float* gw1 = (const float*)d_in[9];
    const float* gb1 = (const float*)d_in[10];
    const float* gw2 = (const float*)d_in[11];
    const float* bng = (const float*)d_in[13];
    const float* bnb = (const float*)d_in[14];

    char* ws = (char*)d_ws;
    float4* xyz4 = (float4*)ws;                        // 256 KB
    int* knn    = (int*)(ws + 262144);                 // 1 MB
    float* Q    = (float*)(ws + 1310720);              // 4 MB
    float* Kf   = (float*)(ws + 5505024);              // 4 MB
    float* Vf   = (float*)(ws + 9699328);              // 4 MB
    float* res  = (float*)(ws + 13893632);             // 4 MB
    float* accum = (float*)(ws + 18087936);            // 512 B
    unsigned short* wbf = (unsigned short*)(ws + 18088448); // 24 KB bf16 qkv weights

    hipMemsetAsync(accum, 0, 512, stream);
    pack_prep<<<67, 256, 0, stream>>>(xyz, xyz4, w_qs, w_ks, w_vs, wbf);
    knnqkv_kernel<<<2304, 256, 0, stream>>>(xyz4, knn, feats, wbf, Q, Kf, Vf);
    attn_mfma<<<1024, 256, 0, stream>>>(xyz4, knn, Q, Kf, Vf, feats,
                                        dw1, db1, dw2, db2, gw1, gb1, gw2, res, accum);
    norm_kernel<<<4096, 256, 0, stream>>>(res, accum, bng, bnb, (float*)d_out);
}